// Round 1
// baseline (260.404 us; speedup 1.0000x reference)
//
#include <hip/hip_runtime.h>

// Net_18966575579675: 722 tiny MLPs (11->10->10->6), B=8192, fp32.
// R5 = R4 with the LDS transpose buffer halved (stage 128 of the 256 output
// rows per pass, two stash/flush passes per chunk). R4 showed Occupancy
// pinned at ~29% (~2.3 blocks/CU) despite grid 2912 and VGPR=72 allowing 7
// waves/SIMD -> residency is LDS-capped (behaves like a ~64KB pool:
// 2x25600 fits, 3x doesn't). LDS 25600 -> 12800 B doubles-plus resident
// blocks so s_load weight latency (the VALUBusy=50% stall) can be hidden.

#define NN 722
#define CAMD 10
#define HD 10
#define LODD 6
#define ROWF (NN * LODD)       // 4332 floats per output row
#define SUB 4                  // batch sub-tiles per wave
#define BT 256                 // batch rows per block (SUB*64)
#define NETS_PER_CHUNK 4       // one net per wave
#define NCHUNKS 181            // ceil(722/4); last chunk has 2 nets
#define CPG 2                  // chunks per y-group
#define NGROUPS 91             // 91*2 = 182 slots >= 181 chunks
#define LSTRIDE 25             // 24 floats + 1 pad (odd -> conflict-free)
#define HROWS 128              // rows staged per flush pass (half of BT)

__global__ __launch_bounds__(256) void Net_18966575579675_kernel(
    const float* __restrict__ prior, const float* __restrict__ camera,
    const float* __restrict__ W1, const float* __restrict__ b1,
    const float* __restrict__ W2, const float* __restrict__ b2,
    const float* __restrict__ W3, const float* __restrict__ b3,
    float* __restrict__ out)
{
    const int tid  = threadIdx.x;
    const int lane = tid & 63;
    // Force wave id (hence net index / all weight addresses) wave-uniform
    // so weight fetches scalarize to s_load.
    const int wave = __builtin_amdgcn_readfirstlane(tid >> 6);
    const int b0   = blockIdx.x * BT;

    const int c_begin = blockIdx.y * CPG;
    const int c_end   = (c_begin + CPG < NCHUNKS) ? (c_begin + CPG) : NCHUNKS;

    __shared__ float lds[HROWS * LSTRIDE];   // 12800 B (was 25600)

    // camera for all 4 sub-tiles -> registers (8B aligned float2 loads)
    float cam[SUB][CAMD];
#pragma unroll
    for (int s = 0; s < SUB; ++s) {
        const float2* cam2 = (const float2*)(camera + (size_t)(b0 + s * 64 + lane) * CAMD);
#pragma unroll
        for (int i = 0; i < CAMD / 2; ++i) {
            float2 v = cam2[i];
            cam[s][2 * i]     = v.x;
            cam[s][2 * i + 1] = v.y;
        }
    }

    for (int c = c_begin; c < c_end; ++c) {
        const int n = c * NETS_PER_CHUNK + wave;   // wave-uniform net index

        float o[SUB][LODD];
        if (n < NN) {
            const float* __restrict__ w1 = W1 + (size_t)n * (CAMD + 1) * HD;
            const float* __restrict__ p1 = b1 + (size_t)n * HD;
            const float* __restrict__ w2 = W2 + (size_t)n * HD * HD;
            const float* __restrict__ p2 = b2 + (size_t)n * HD;
            const float* __restrict__ w3 = W3 + (size_t)n * HD * LODD;
            const float* __restrict__ p3 = b3 + (size_t)n * LODD;

            float pr[SUB];
#pragma unroll
            for (int s = 0; s < SUB; ++s)
                pr[s] = prior[(size_t)(b0 + s * 64 + lane) * NN + n];

            // ---- layer 1: h1 = relu(x @ W1 + b1), x = [prior, cam] ----
            float h1[SUB][HD];
#pragma unroll
            for (int j = 0; j < HD; ++j) {
                const float bj = p1[j];
                const float w  = w1[j];              // W1 row 0 (prior input)
#pragma unroll
                for (int s = 0; s < SUB; ++s)
                    h1[s][j] = fmaf(pr[s], w, bj);
            }
#pragma unroll
            for (int i = 0; i < CAMD; ++i) {
#pragma unroll
                for (int j = 0; j < HD; ++j) {
                    const float w = w1[(i + 1) * HD + j];   // contiguous s_loads
#pragma unroll
                    for (int s = 0; s < SUB; ++s)
                        h1[s][j] = fmaf(cam[s][i], w, h1[s][j]);
                }
            }
#pragma unroll
            for (int s = 0; s < SUB; ++s)
#pragma unroll
                for (int j = 0; j < HD; ++j)
                    h1[s][j] = fmaxf(h1[s][j], 0.0f);

            // ---- layer 2: h2 = relu(h1 @ W2 + b2) ----
            float h2[SUB][HD];
#pragma unroll
            for (int k = 0; k < HD; ++k) {
                const float bk = p2[k];
#pragma unroll
                for (int s = 0; s < SUB; ++s)
                    h2[s][k] = bk;
            }
#pragma unroll
            for (int j = 0; j < HD; ++j) {
#pragma unroll
                for (int k = 0; k < HD; ++k) {
                    const float w = w2[j * HD + k];
#pragma unroll
                    for (int s = 0; s < SUB; ++s)
                        h2[s][k] = fmaf(h1[s][j], w, h2[s][k]);
                }
            }
#pragma unroll
            for (int s = 0; s < SUB; ++s)
#pragma unroll
                for (int k = 0; k < HD; ++k)
                    h2[s][k] = fmaxf(h2[s][k], 0.0f);

            // ---- layer 3: o = h2 @ W3 + b3 ----
#pragma unroll
            for (int m = 0; m < LODD; ++m) {
                const float bm = p3[m];
#pragma unroll
                for (int s = 0; s < SUB; ++s)
                    o[s][m] = bm;
            }
#pragma unroll
            for (int j = 0; j < HD; ++j) {
#pragma unroll
                for (int m = 0; m < LODD; ++m) {
                    const float w = w3[j * LODD + m];
#pragma unroll
                    for (int s = 0; s < SUB; ++s)
                        o[s][m] = fmaf(h2[s][j], w, o[s][m]);
                }
            }
        }

        const int rem = NN - c * NETS_PER_CHUNK;
        const int nv  = rem < NETS_PER_CHUNK ? rem : NETS_PER_CHUNK;

        // two stash/flush passes: rows [0,128) then [128,256)
#pragma unroll
        for (int p = 0; p < 2; ++p) {
            if (n < NN) {
#pragma unroll
                for (int ss = 0; ss < 2; ++ss)
#pragma unroll
                    for (int m = 0; m < LODD; ++m)
                        lds[(ss * 64 + lane) * LSTRIDE + wave * LODD + m] = o[2 * p + ss][m];
            }
            __syncthreads();

            // flush: nv nets * 6 floats per row, HROWS rows, aligned float4 runs
            if (nv == NETS_PER_CHUNK) {
                // common case: nq = 6 (compile-time divide)
                for (int f = tid; f < HROWS * 6; f += 256) {
                    const int row  = f / 6;
                    const int colq = f - row * 6;
                    const float* s = lds + row * LSTRIDE + colq * 4;
                    float4 v = make_float4(s[0], s[1], s[2], s[3]);
                    *(float4*)(out + (size_t)(b0 + p * HROWS + row) * ROWF
                               + c * (NETS_PER_CHUNK * LODD) + colq * 4) = v;
                }
            } else {
                // last chunk: nv = 2 -> nq = 3 (compile-time divide)
                for (int f = tid; f < HROWS * 3; f += 256) {
                    const int row  = f / 3;
                    const int colq = f - row * 3;
                    const float* s = lds + row * LSTRIDE + colq * 4;
                    float4 v = make_float4(s[0], s[1], s[2], s[3]);
                    *(float4*)(out + (size_t)(b0 + p * HROWS + row) * ROWF
                               + c * (NETS_PER_CHUNK * LODD) + colq * 4) = v;
                }
            }
            __syncthreads();
        }
    }
}

extern "C" void kernel_launch(void* const* d_in, const int* in_sizes, int n_in,
                              void* d_out, int out_size, void* d_ws, size_t ws_size,
                              hipStream_t stream) {
    const float* prior  = (const float*)d_in[0];
    const float* camera = (const float*)d_in[1];
    const float* W1     = (const float*)d_in[2];
    const float* b1     = (const float*)d_in[3];
    const float* W2     = (const float*)d_in[4];
    const float* b2     = (const float*)d_in[5];
    const float* W3     = (const float*)d_in[6];
    const float* b3     = (const float*)d_in[7];
    float* out = (float*)d_out;

    dim3 grid(8192 / BT, NGROUPS);   // 32 x 91 = 2912 blocks (~11/CU)
    dim3 block(256);
    Net_18966575579675_kernel<<<grid, block, 0, stream>>>(
        prior, camera, W1, b1, W2, b2, W3, b3, out);
}

// Round 2
// 250.010 us; speedup vs baseline: 1.0416x; 1.0416x over previous
//
#include <hip/hip_runtime.h>

// Net_18966575579675: 722 tiny MLPs (11->10->10->6), B=8192, fp32.
// R6: barrier-drain elimination. R4/R5 showed occupancy (30%) and VALUBusy
// (51% = "any SIMD busy" ~= 20%/SIMD) invariant to grid 3x and LDS /2 ->
// latency-bound, waves ~80% stalled, and the invariant cost is the
// __syncthreads() vmcnt(0) drain of flush global-stores at every barrier.
// Changes vs R4/R5:
//  * double-buffered 128-row LDS stash (2 x 12800 B = R4 footprint) so the
//    barrier only orders LDS traffic,
//  * raw `s_waitcnt lgkmcnt(0)` + s_barrier (no vmcnt drain): out-stores
//    stay in flight and ack under the next chunk's ~2600-cycle compute,
//  * prior gather prefetched one chunk ahead (scattered ~900cy loads hide
//    under compute instead of serializing at the chunk head).

#define NN 722
#define CAMD 10
#define HD 10
#define LODD 6
#define ROWF (NN * LODD)       // 4332 floats per output row
#define SUB 4                  // batch sub-tiles per wave
#define BT 256                 // batch rows per block (SUB*64)
#define NETS_PER_CHUNK 4       // one net per wave
#define NCHUNKS 181            // ceil(722/4); last chunk has 2 nets
#define CPG 2                  // chunks per y-group
#define NGROUPS 91             // 91*2 = 182 slots >= 181 chunks
#define LSTRIDE 25             // 24 floats + 1 pad (odd -> conflict-free)
#define HROWS 128              // rows staged per flush pass (half of BT)

// LDS-only barrier: order ds_write/ds_read across waves WITHOUT draining
// vmcnt (global stores / prefetch loads stay in flight). The "memory"
// clobber pins all memory ops on both sides of the waitcnt.
__device__ __forceinline__ void lds_barrier() {
    asm volatile("s_waitcnt lgkmcnt(0)" ::: "memory");
    __builtin_amdgcn_s_barrier();
}

__global__ __launch_bounds__(256) void Net_18966575579675_kernel(
    const float* __restrict__ prior, const float* __restrict__ camera,
    const float* __restrict__ W1, const float* __restrict__ b1,
    const float* __restrict__ W2, const float* __restrict__ b2,
    const float* __restrict__ W3, const float* __restrict__ b3,
    float* __restrict__ out)
{
    const int tid  = threadIdx.x;
    const int lane = tid & 63;
    // Force wave id (hence net index / all weight addresses) wave-uniform
    // so weight fetches scalarize to s_load.
    const int wave = __builtin_amdgcn_readfirstlane(tid >> 6);
    const int b0   = blockIdx.x * BT;

    const int c_begin = blockIdx.y * CPG;
    const int c_end   = (c_begin + CPG < NCHUNKS) ? (c_begin + CPG) : NCHUNKS;

    __shared__ float lds[2][HROWS * LSTRIDE];   // 2 x 12800 B double buffer

    // camera for all 4 sub-tiles -> registers (8B aligned float2 loads)
    float cam[SUB][CAMD];
#pragma unroll
    for (int s = 0; s < SUB; ++s) {
        const float2* cam2 = (const float2*)(camera + (size_t)(b0 + s * 64 + lane) * CAMD);
#pragma unroll
        for (int i = 0; i < CAMD / 2; ++i) {
            float2 v = cam2[i];
            cam[s][2 * i]     = v.x;
            cam[s][2 * i + 1] = v.y;
        }
    }

    // prefetch prior gather for the first chunk (clamped index; values of
    // clamped lanes are never used)
    float pr[SUB];
    {
        const int n0 = c_begin * NETS_PER_CHUNK + wave;
        const int nc = n0 < NN ? n0 : NN - 1;
#pragma unroll
        for (int s = 0; s < SUB; ++s)
            pr[s] = prior[(size_t)(b0 + s * 64 + lane) * NN + nc];
    }

    int g = 0;   // LDS buffer toggle (per stash/flush pass)

    for (int c = c_begin; c < c_end; ++c) {
        const int n = c * NETS_PER_CHUNK + wave;   // wave-uniform net index

        // issue NEXT chunk's prior gather now -> ~900cy latency hides under
        // this chunk's compute (barriers below never drain vmcnt)
        float prn[SUB];
        if (c + 1 < c_end) {
            const int n1 = (c + 1) * NETS_PER_CHUNK + wave;
            const int nc = n1 < NN ? n1 : NN - 1;
#pragma unroll
            for (int s = 0; s < SUB; ++s)
                prn[s] = prior[(size_t)(b0 + s * 64 + lane) * NN + nc];
        }

        float o[SUB][LODD];
        if (n < NN) {
            const float* __restrict__ w1 = W1 + (size_t)n * (CAMD + 1) * HD;
            const float* __restrict__ p1 = b1 + (size_t)n * HD;
            const float* __restrict__ w2 = W2 + (size_t)n * HD * HD;
            const float* __restrict__ p2 = b2 + (size_t)n * HD;
            const float* __restrict__ w3 = W3 + (size_t)n * HD * LODD;
            const float* __restrict__ p3 = b3 + (size_t)n * LODD;

            // ---- layer 1: h1 = relu(x @ W1 + b1), x = [prior, cam] ----
            float h1[SUB][HD];
#pragma unroll
            for (int j = 0; j < HD; ++j) {
                const float bj = p1[j];
                const float w  = w1[j];              // W1 row 0 (prior input)
#pragma unroll
                for (int s = 0; s < SUB; ++s)
                    h1[s][j] = fmaf(pr[s], w, bj);
            }
#pragma unroll
            for (int i = 0; i < CAMD; ++i) {
#pragma unroll
                for (int j = 0; j < HD; ++j) {
                    const float w = w1[(i + 1) * HD + j];   // contiguous s_loads
#pragma unroll
                    for (int s = 0; s < SUB; ++s)
                        h1[s][j] = fmaf(cam[s][i], w, h1[s][j]);
                }
            }
#pragma unroll
            for (int s = 0; s < SUB; ++s)
#pragma unroll
                for (int j = 0; j < HD; ++j)
                    h1[s][j] = fmaxf(h1[s][j], 0.0f);

            // ---- layer 2: h2 = relu(h1 @ W2 + b2) ----
            float h2[SUB][HD];
#pragma unroll
            for (int k = 0; k < HD; ++k) {
                const float bk = p2[k];
#pragma unroll
                for (int s = 0; s < SUB; ++s)
                    h2[s][k] = bk;
            }
#pragma unroll
            for (int j = 0; j < HD; ++j) {
#pragma unroll
                for (int k = 0; k < HD; ++k) {
                    const float w = w2[j * HD + k];
#pragma unroll
                    for (int s = 0; s < SUB; ++s)
                        h2[s][k] = fmaf(h1[s][j], w, h2[s][k]);
                }
            }
#pragma unroll
            for (int s = 0; s < SUB; ++s)
#pragma unroll
                for (int k = 0; k < HD; ++k)
                    h2[s][k] = fmaxf(h2[s][k], 0.0f);

            // ---- layer 3: o = h2 @ W3 + b3 ----
#pragma unroll
            for (int m = 0; m < LODD; ++m) {
                const float bm = p3[m];
#pragma unroll
                for (int s = 0; s < SUB; ++s)
                    o[s][m] = bm;
            }
#pragma unroll
            for (int j = 0; j < HD; ++j) {
#pragma unroll
                for (int m = 0; m < LODD; ++m) {
                    const float w = w3[j * LODD + m];
#pragma unroll
                    for (int s = 0; s < SUB; ++s)
                        o[s][m] = fmaf(h2[s][j], w, o[s][m]);
                }
            }
        }

        const int rem = NN - c * NETS_PER_CHUNK;
        const int nv  = rem < NETS_PER_CHUNK ? rem : NETS_PER_CHUNK;

        // two stash/flush passes, alternating LDS buffers; barriers are
        // LDS-only so flush stores overlap the next pass / next chunk
#pragma unroll
        for (int p = 0; p < 2; ++p) {
            float* lbuf = lds[g];
            if (n < NN) {
#pragma unroll
                for (int ss = 0; ss < 2; ++ss)
#pragma unroll
                    for (int m = 0; m < LODD; ++m)
                        lbuf[(ss * 64 + lane) * LSTRIDE + wave * LODD + m] = o[2 * p + ss][m];
            }
            lds_barrier();   // order stash writes vs flush reads (no vmcnt)

            // flush: nv nets * 6 floats per row, HROWS rows, float4 runs
            if (nv == NETS_PER_CHUNK) {
                // common case: nq = 6 (compile-time divide)
                for (int f = tid; f < HROWS * 6; f += 256) {
                    const int row  = f / 6;
                    const int colq = f - row * 6;
                    const float* s = lbuf + row * LSTRIDE + colq * 4;
                    float4 v = make_float4(s[0], s[1], s[2], s[3]);
                    *(float4*)(out + (size_t)(b0 + p * HROWS + row) * ROWF
                               + c * (NETS_PER_CHUNK * LODD) + colq * 4) = v;
                }
            } else {
                // last chunk: nv = 2 -> nq = 3 (compile-time divide)
                for (int f = tid; f < HROWS * 3; f += 256) {
                    const int row  = f / 3;
                    const int colq = f - row * 3;
                    const float* s = lbuf + row * LSTRIDE + colq * 4;
                    float4 v = make_float4(s[0], s[1], s[2], s[3]);
                    *(float4*)(out + (size_t)(b0 + p * HROWS + row) * ROWF
                               + c * (NETS_PER_CHUNK * LODD) + colq * 4) = v;
                }
            }
            g ^= 1;
            // no second barrier: next stash targets the OTHER buffer; reuse
            // of THIS buffer happens after the next pass's lds_barrier, by
            // which time every wave's flush reads are lgkmcnt(0)-complete.
        }

        // rotate prefetched prior into place (dead values if loop ends)
#pragma unroll
        for (int s = 0; s < SUB; ++s)
            pr[s] = prn[s];
    }
}

extern "C" void kernel_launch(void* const* d_in, const int* in_sizes, int n_in,
                              void* d_out, int out_size, void* d_ws, size_t ws_size,
                              hipStream_t stream) {
    const float* prior  = (const float*)d_in[0];
    const float* camera = (const float*)d_in[1];
    const float* W1     = (const float*)d_in[2];
    const float* b1     = (const float*)d_in[3];
    const float* W2     = (const float*)d_in[4];
    const float* b2     = (const float*)d_in[5];
    const float* W3     = (const float*)d_in[6];
    const float* b3     = (const float*)d_in[7];
    float* out = (float*)d_out;

    dim3 grid(8192 / BT, NGROUPS);   // 32 x 91 = 2912 blocks
    dim3 block(256);
    Net_18966575579675_kernel<<<grid, block, 0, stream>>>(
        prior, camera, W1, b1, W2, b2, W3, b3, out);
}